// Round 3
// baseline (434.302 us; speedup 1.0000x reference)
//
#include <hip/hip_runtime.h>
#include <hip/hip_bf16.h>
#include <cstdint>

using bf16 = __hip_bfloat16;
typedef __bf16 bf16x8 __attribute__((ext_vector_type(8)));
typedef float f32x4 __attribute__((ext_vector_type(4)));

#define DEV static __device__ __forceinline__

DEV float toF(float x) { return x; }
DEV float toF(bf16 x) { return __bfloat162float(x); }

DEV unsigned int bfbits(float f) {  // f32 -> bf16 bits, RNE
  unsigned int u = __builtin_bit_cast(unsigned int, f);
  return (u + 0x7fffu + ((u >> 16) & 1u)) >> 16;
}
DEV float lo2f(unsigned int u) { return __builtin_bit_cast(float, u << 16); }
DEV float hi2f(unsigned int u) { return __builtin_bit_cast(float, u & 0xffff0000u); }

// async global->LDS, 16B per lane. LDS dest = wave-uniform base + lane*16.
DEV void gload_lds16(const void* g, void* l) {
  __builtin_amdgcn_global_load_lds(
      (const __attribute__((address_space(1))) unsigned int*)g,
      (__attribute__((address_space(3))) unsigned int*)l, 16, 0, 0);
}

// C[m][n] = alpha * sum_k A[m][k] * BT[n][k]  (+ bias[m] or bias[n])
// 64x128 tile, BK=32, 4 waves (2x2), 1024-block grids for 4 blocks/CU.
template <int BM, int BN, bool OUT_BF16, bool BIAS_COL>
__launch_bounds__(256, 4)
__global__ void gemm_bt(const bf16* __restrict__ A, long long sA,
                        const bf16* __restrict__ B, long long sB,
                        void* __restrict__ Cv, long long sC,
                        const float* __restrict__ bias,
                        int K, int lda, int ldb, int ldc, float alpha) {
  constexpr int BK = 32;
  __shared__ bf16 ldsA[BM * BK];
  __shared__ bf16 ldsB[BN * BK];
  const int tid = threadIdx.x;
  const int wave = tid >> 6, lane = tid & 63;
  const long long z = blockIdx.z;
  A += z * sA;
  B += z * sB;
  const int m0 = blockIdx.y * BM, n0 = blockIdx.x * BN;

  constexpr int WM = BM / 2, WN = BN / 2;
  constexpr int MR = WM / 16, NR = WN / 16;
  const int wm = (wave >> 1) * WM, wn = (wave & 1) * WN;
  const int lrow = lane & 15;
  const int kb = (lane >> 4) * 8;

  f32x4 acc[MR][NR] = {};

  for (int k0 = 0; k0 < K; k0 += BK) {
#pragma unroll
    for (int r = 0; r < BM / 64; ++r) {
      int c = r * 256 + tid;
      int row = c >> 2, sub = c & 3;
      gload_lds16(A + (long long)(m0 + row) * lda + k0 + sub * 8,
                  (void*)(ldsA + (r * 256 + wave * 64) * 8));
    }
#pragma unroll
    for (int r = 0; r < BN / 64; ++r) {
      int c = r * 256 + tid;
      int row = c >> 2, sub = c & 3;
      gload_lds16(B + (long long)(n0 + row) * ldb + k0 + sub * 8,
                  (void*)(ldsB + (r * 256 + wave * 64) * 8));
    }
    __syncthreads();

    bf16x8 af[MR], bfr[NR];
#pragma unroll
    for (int i = 0; i < MR; ++i)
      af[i] = *(const bf16x8*)&ldsA[(wm + i * 16 + lrow) * BK + kb];
#pragma unroll
    for (int j = 0; j < NR; ++j)
      bfr[j] = *(const bf16x8*)&ldsB[(wn + j * 16 + lrow) * BK + kb];
#pragma unroll
    for (int i = 0; i < MR; ++i)
#pragma unroll
      for (int j = 0; j < NR; ++j)
        acc[i][j] =
            __builtin_amdgcn_mfma_f32_16x16x32_bf16(af[i], bfr[j], acc[i][j], 0, 0, 0);
    __syncthreads();
  }

  const int r4 = (lane >> 4) * 4;
#pragma unroll
  for (int i = 0; i < MR; ++i) {
#pragma unroll
    for (int j = 0; j < NR; ++j) {
#pragma unroll
      for (int r = 0; r < 4; ++r) {
        int grow = m0 + wm + i * 16 + r4 + r;
        int gcol = n0 + wn + j * 16 + lrow;
        float vv = acc[i][j][r] * alpha;
        if (bias) vv += BIAS_COL ? bias[gcol] : bias[grow];
        if constexpr (OUT_BF16)
          ((bf16*)Cv)[z * sC + (long long)grow * ldc + gcol] = __float2bfloat16(vv);
        else
          ((float*)Cv)[z * sC + (long long)grow * ldc + gcol] = vv;
      }
    }
  }
}

// bank swizzle for S/P LDS (u32-indexed [hp][16 m][32 mm]): mm ^= SW(m)
DEV int SW(int m) { return (m & 12) | ((m & 4) << 2); }

// Fused score(QK^T/8) -> 16-head softmax -> PV. m-tile 16, 512 blocks, 8 waves.
// S/P packed as (h_even lo | h_odd hi) u32; 2 barriers/iter.
__launch_bounds__(512, 4)
__global__ void fused_attn(const bf16* __restrict__ qp,
                           const bf16* __restrict__ kpT,
                           const bf16* __restrict__ vpT,
                           bf16* __restrict__ aout) {
  __shared__ unsigned int Su[8 * 16 * 32];  // 16KB
  __shared__ unsigned int Pu[8 * 16 * 32];  // 16KB
  const int bid = blockIdx.x;
  const int bb = bid & 7, mt = bid >> 3;  // batch -> XCD (K/V L2-resident)
  const int m0 = mt * 16;
  const int tid = threadIdx.x;
  const int wave = tid >> 6, lane = tid & 63;
  const int lrow = lane & 15, g = lane >> 4;
  const int kb8 = g * 8, r4 = g * 4;
  const int h0 = wave * 2;

  const bf16* Qb = qp + ((size_t)bb << 20);
  const bf16* Kb = kpT + ((size_t)bb << 20);
  const bf16* Vb = vpT + ((size_t)bb << 20);
  bf16* Ob = aout + ((size_t)bb << 20);

  // hoist Q fragments (A: rows m, k = dt)
  bf16x8 qf[2][2];
#pragma unroll
  for (int h = 0; h < 2; ++h)
#pragma unroll
    for (int kc = 0; kc < 2; ++kc)
      qf[h][kc] = *(const bf16x8*)(Qb + ((size_t)(h0 + h) << 16) +
                                   (m0 + lrow) * 64 + kc * 32 + kb8);

  f32x4 oacc[2][4] = {};
  const int sm_m = tid >> 5, sm_mm = tid & 31;
  const int sm_base = sm_m * 32 + (sm_mm ^ SW(sm_m));
  const int pv_base = wave * 512 + lrow * 32 + (kb8 ^ SW(lrow));

  for (int t = 0; t < 32; ++t) {
    const int n0 = t * 32;
    // ---- QK^T ----
    f32x4 sacc[2][2] = {};
    __builtin_amdgcn_s_setprio(1);
#pragma unroll
    for (int h = 0; h < 2; ++h)
#pragma unroll
      for (int kc = 0; kc < 2; ++kc) {
        bf16x8 kf0 = *(const bf16x8*)(Kb + (size_t)(n0 + lrow) * 1024 +
                                      ((h0 + h) << 6) + kc * 32 + kb8);
        bf16x8 kf1 = *(const bf16x8*)(Kb + (size_t)(n0 + 16 + lrow) * 1024 +
                                      ((h0 + h) << 6) + kc * 32 + kb8);
        sacc[h][0] = __builtin_amdgcn_mfma_f32_16x16x32_bf16(qf[h][kc], kf0, sacc[h][0], 0, 0, 0);
        sacc[h][1] = __builtin_amdgcn_mfma_f32_16x16x32_bf16(qf[h][kc], kf1, sacc[h][1], 0, 0, 0);
      }
    __builtin_amdgcn_s_setprio(0);
    // ---- early V-fragment issue (hides L2 latency under softmax) ----
    bf16x8 vf[2][4];
#pragma unroll
    for (int h = 0; h < 2; ++h)
#pragma unroll
      for (int dj = 0; dj < 4; ++dj)
        vf[h][dj] = *(const bf16x8*)(Vb + (size_t)((h0 + h) * 64 + dj * 16 + lrow) * 1024 +
                                     n0 + kb8);
    // ---- pack S (bf16 head-pair) ----
#pragma unroll
    for (int nj = 0; nj < 2; ++nj)
#pragma unroll
      for (int r = 0; r < 4; ++r) {
        int m = r4 + r, mm = nj * 16 + lrow;
        unsigned int u = bfbits(sacc[0][nj][r] * 0.125f) |
                         (bfbits(sacc[1][nj][r] * 0.125f) << 16);
        Su[wave * 512 + m * 32 + (mm ^ SW(m))] = u;
      }
    __syncthreads();
    // ---- softmax over 16 heads at one (m,mm) per thread ----
    {
      float vals[16];
#pragma unroll
      for (int hp = 0; hp < 8; ++hp) {
        unsigned int u = Su[hp * 512 + sm_base];
        vals[2 * hp] = lo2f(u);
        vals[2 * hp + 1] = hi2f(u);
      }
      float mx = vals[0];
#pragma unroll
      for (int s = 1; s < 16; ++s) mx = fmaxf(mx, vals[s]);
      float sum = 0.f;
#pragma unroll
      for (int s = 0; s < 16; ++s) {
        vals[s] = __expf(vals[s] - mx);
        sum += vals[s];
      }
      float inv = 1.0f / sum;
#pragma unroll
      for (int hp = 0; hp < 8; ++hp)
        Pu[hp * 512 + sm_base] =
            bfbits(vals[2 * hp] * inv) | (bfbits(vals[2 * hp + 1] * inv) << 16);
    }
    __syncthreads();
    // ---- PV: unpack A-frags for this wave's 2 heads, accumulate ----
    {
      uint4 a = *(const uint4*)&Pu[pv_base];
      uint4 b = *(const uint4*)&Pu[pv_base ^ 4];
      unsigned int e[4] = {(a.x & 0xffffu) | (a.y << 16), (a.z & 0xffffu) | (a.w << 16),
                           (b.x & 0xffffu) | (b.y << 16), (b.z & 0xffffu) | (b.w << 16)};
      unsigned int o[4] = {(a.x >> 16) | (a.y & 0xffff0000u), (a.z >> 16) | (a.w & 0xffff0000u),
                           (b.x >> 16) | (b.y & 0xffff0000u), (b.z >> 16) | (b.w & 0xffff0000u)};
      bf16x8 paE = __builtin_bit_cast(bf16x8, *(uint4*)e);
      bf16x8 paO = __builtin_bit_cast(bf16x8, *(uint4*)o);
      __builtin_amdgcn_s_setprio(1);
#pragma unroll
      for (int dj = 0; dj < 4; ++dj) {
        oacc[0][dj] = __builtin_amdgcn_mfma_f32_16x16x32_bf16(paE, vf[0][dj], oacc[0][dj], 0, 0, 0);
        oacc[1][dj] = __builtin_amdgcn_mfma_f32_16x16x32_bf16(paO, vf[1][dj], oacc[1][dj], 0, 0, 0);
      }
      __builtin_amdgcn_s_setprio(0);
    }
    // no third barrier: B1(t+1) guards Pu writes vs our reads; Su writes vs
    // softmax reads are guarded by B2(t).
  }
  // ---- write out flat (h, m, dt) concat layout ----
#pragma unroll
  for (int h = 0; h < 2; ++h)
#pragma unroll
    for (int dj = 0; dj < 4; ++dj)
#pragma unroll
      for (int r = 0; r < 4; ++r)
        Ob[((size_t)(h0 + h) << 16) + (size_t)(m0 + r4 + r) * 64 + dj * 16 + lrow] =
            __float2bfloat16(oacc[h][dj][r]);
}

// out[c][r] = (bf16) in[r][c]
template <typename TIN>
__global__ void transpose_tile(const TIN* __restrict__ in, bf16* __restrict__ out,
                               int R, int C, long long sIn, long long sOut) {
  __shared__ float t[32][33];
  const long long z = blockIdx.z;
  in += z * sIn;
  out += z * sOut;
  const int r0 = blockIdx.y * 32, c0 = blockIdx.x * 32;
  const int tx = threadIdx.x, ty = threadIdx.y;
#pragma unroll
  for (int i = ty; i < 32; i += 8)
    t[i][tx] = toF(in[(long long)(r0 + i) * C + c0 + tx]);
  __syncthreads();
#pragma unroll
  for (int i = ty; i < 32; i += 8)
    out[(long long)(c0 + i) * R + r0 + tx] = __float2bfloat16(t[tx][i]);
}

// 3 input transposes (f32 [c][l] -> bf16 [l][c]) in one launch; z = 0..23
__global__ void transpose_in3(const float* __restrict__ q, const float* __restrict__ k,
                              const float* __restrict__ v, bf16* __restrict__ qT,
                              bf16* __restrict__ kT, bf16* __restrict__ vT) {
  __shared__ float t[32][33];
  const int z = blockIdx.z, bz = z & 7, which = z >> 3;
  const float* in = (which == 0 ? q : which == 1 ? k : v) + (size_t)bz * 1048576;
  bf16* out = (which == 0 ? qT : which == 1 ? kT : vT) + (size_t)bz * 1048576;
  const int r0 = blockIdx.y * 32, c0 = blockIdx.x * 32;
  const int tx = threadIdx.x, ty = threadIdx.y;
#pragma unroll
  for (int i = ty; i < 32; i += 8)
    t[i][tx] = in[(size_t)(r0 + i) * 1024 + c0 + tx];
  __syncthreads();
#pragma unroll
  for (int i = ty; i < 32; i += 8)
    out[(size_t)(c0 + i) * 1024 + r0 + tx] = __float2bfloat16(t[tx][i]);
}

// 4 weight casts in one launch; y selects the weight
__global__ void cast4(const float* __restrict__ w0, const float* __restrict__ w1,
                      const float* __restrict__ w2, const float* __restrict__ w3,
                      bf16* __restrict__ o0, bf16* __restrict__ o1,
                      bf16* __restrict__ o2, bf16* __restrict__ o3) {
  const int y = blockIdx.y;
  const float* in = y == 0 ? w0 : y == 1 ? w1 : y == 2 ? w2 : w3;
  bf16* out = y == 0 ? o0 : y == 1 ? o1 : y == 2 ? o2 : o3;
  int i = (blockIdx.x * 256 + threadIdx.x) * 4;
  float4 f = *(const float4*)(in + i);
  out[i + 0] = __float2bfloat16(f.x);
  out[i + 1] = __float2bfloat16(f.y);
  out[i + 2] = __float2bfloat16(f.z);
  out[i + 3] = __float2bfloat16(f.w);
}

extern "C" void kernel_launch(void* const* d_in, const int* in_sizes, int n_in,
                              void* d_out, int out_size, void* d_ws, size_t ws_size,
                              hipStream_t stream) {
  (void)in_sizes; (void)n_in; (void)out_size;
  const float* q  = (const float*)d_in[0];
  const float* k  = (const float*)d_in[1];
  const float* v  = (const float*)d_in[2];
  const float* Wq = (const float*)d_in[3];
  const float* bq = (const float*)d_in[4];
  const float* Wk = (const float*)d_in[5];
  const float* bk = (const float*)d_in[6];
  const float* Wv = (const float*)d_in[7];
  const float* bv = (const float*)d_in[8];
  const float* Wo = (const float*)d_in[9];
  const float* bo = (const float*)d_in[10];
  float* out = (float*)d_out;

  const size_t MB = 1ull << 20;
  if (ws_size < 152 * MB) return;
  char* ws = (char*)d_ws;
  bf16* qp    = (bf16*)(ws + 0 * MB);   // [B][16][1024][64] head-blocked
  bf16* kpT   = (bf16*)(ws + 16 * MB);  // [B][1024 m'][1024 o]
  bf16* vpT   = (bf16*)(ws + 32 * MB);  // [B][16][64][1024]
  bf16* aout  = (bf16*)(ws + 48 * MB);  // [B] flat concat (h,m,d) == [ml][l]
  bf16* aoutT = (bf16*)(ws + 64 * MB);  // [B][l][ml]
  bf16* WoB   = (bf16*)(ws + 80 * MB);
  char* scr = ws + 82 * MB;
  bf16* WqB = (bf16*)(scr + 0 * MB);
  bf16* WkB = (bf16*)(scr + 2 * MB);
  bf16* WvB = (bf16*)(scr + 4 * MB);
  bf16* qT  = (bf16*)(scr + 6 * MB);
  bf16* kT  = (bf16*)(scr + 22 * MB);
  bf16* vT  = (bf16*)(scr + 38 * MB);
  bf16* vp  = (bf16*)(scr + 54 * MB);

  const long long M1 = 1048576, HB = 65536;
  dim3 tb(32, 8);

  cast4<<<dim3(1024, 4), 256, 0, stream>>>(Wq, Wk, Wv, Wo, WqB, WkB, WvB, WoB);
  transpose_in3<<<dim3(32, 32, 24), tb, 0, stream>>>(q, k, v, qT, kT, vT);
  // qp[o][l] = Wq . q  (bias rows)
  gemm_bt<64, 128, true, false><<<dim3(8, 16, 8), 256, 0, stream>>>(
      WqB, 0, qT, M1, qp, M1, bq, 1024, 1024, 1024, 1024, 1.0f);
  // kpT[l][o] = (Wk . k)^T directly (bias cols)
  gemm_bt<64, 128, true, true><<<dim3(8, 16, 8), 256, 0, stream>>>(
      kT, M1, WkB, 0, kpT, M1, bk, 1024, 1024, 1024, 1024, 1.0f);
  gemm_bt<64, 128, true, false><<<dim3(8, 16, 8), 256, 0, stream>>>(
      WvB, 0, vT, M1, vp, M1, bv, 1024, 1024, 1024, 1024, 1.0f);
  // per-(b,h) V^T: head block [1024][64] -> [64][1024]
  transpose_tile<bf16><<<dim3(2, 32, 128), tb, 0, stream>>>(vp, vpT, 1024, 64, HB, HB);

  fused_attn<<<dim3(512), 512, 0, stream>>>(qp, kpT, vpT, aout);

  transpose_tile<bf16><<<dim3(32, 32, 8), tb, 0, stream>>>(aout, aoutT, 1024, 1024, M1, M1);
  gemm_bt<64, 128, false, false><<<dim3(8, 16, 8), 256, 0, stream>>>(
      WoB, 0, aoutT, M1, out, M1, bo, 1024, 1024, 1024, 1024, 1.0f);
}